// Round 19
// baseline (186.973 us; speedup 1.0000x reference)
//
#include <hip/hip_runtime.h>
#include <stdint.h>

#define Bn 64
#define Sn 512
#define SPn 520
#define Dn 768
#define JSTRIDE 196608   // 256 rows * 768 B : tap stride within wq
#define ABUF 16640       // 260 rows * 64 B
#define QS_A 28.222222f  // 127/4.5
#define SAQ 0.035433072f // 4.5/127

typedef int iv4 __attribute__((ext_vector_type(4)));

static __device__ __forceinline__ signed char q8(float f, float s) {
  float t = __builtin_rintf(f * s);
  t = fmaxf(-127.f, fminf(127.f, t));
  return (signed char)(int)t;
}

// async global->LDS, 16B/lane; LDS dest = wave-uniform base + lane*16
static __device__ __forceinline__ void gload16(const void* g, void* l) {
  __builtin_amdgcn_global_load_lds(
      (const __attribute__((address_space(1))) unsigned int*)g,
      (__attribute__((address_space(3))) unsigned int*)l, 16, 0, 0);
}

// ---------------------------------------------------------------------------
// 1) fused stage: blocks [0,512) compact+quant h -> hcq (rblk 0 writes L);
//    [512,1536) wpack
// ---------------------------------------------------------------------------
__global__ __launch_bounds__(256) void stage_kernel(
    const int* __restrict__ x, const float* __restrict__ h,
    const float* __restrict__ w2, const float* __restrict__ w3,
    const float* __restrict__ w4, const float* __restrict__ w5,
    signed char* __restrict__ hcq, signed char* __restrict__ wq,
    float* __restrict__ fscale, int* __restrict__ Lout) {
  int tid = threadIdx.x, lane = tid & 63, wv = tid >> 6;
  if (blockIdx.x < 512) {
    int cidx = blockIdx.x;
    int b = cidx >> 3, rblk = cidx & 7;
    __shared__ unsigned long long masks[8];
    __shared__ short sidx[Sn];
    for (int c = wv; c < 8; c += 4) {
      unsigned long long m = __ballot(x[b * Sn + c * 64 + lane] != 0);
      if (lane == 0) masks[c] = m;
    }
    __syncthreads();
    int pref[9]; pref[0] = 0;
    #pragma unroll
    for (int c = 0; c < 8; ++c) pref[c + 1] = pref[c] + __popcll(masks[c]);
    int L = pref[8];
    if (rblk == 0 && tid == 0) Lout[b] = L;
    for (int p = tid; p < Sn; p += 256) {
      int c = p >> 6, l = p & 63;
      unsigned long long m = masks[c];
      if ((m >> l) & 1ull)
        sidx[pref[c] + __popcll(m & ((1ull << l) - 1ull))] = (short)p;
    }
    __syncthreads();
    int r0 = rblk * 65;  // 8 * 65 = 520 rows
    for (int r = r0 + wv; r < r0 + 65; r += 4) {
      if (r < L) {
        signed char* dst = hcq + ((size_t)b * SPn + r) * Dn;
        const float* src = h + ((size_t)b * Sn + sidx[r]) * Dn;
        #pragma unroll
        for (int c = 0; c < 3; ++c) {
          int d = c * 256 + lane * 4;
          float4 v = *(const float4*)(src + d);
          char4 o = { q8(v.x, QS_A), q8(v.y, QS_A), q8(v.z, QS_A), q8(v.w, QS_A) };
          *(char4*)(dst + d) = o;
        }
      }
    }
  } else {
    __shared__ float sf[3840];
    __shared__ float smax[4];
    int bb = blockIdx.x - 512;
    int br = bb >> 8, f = bb & 255, k = br + 2;
    const float* w = (br == 0) ? w2 : (br == 1) ? w3 : (br == 2) ? w4 : w5;
    int mBase = 256 * ((br * (br + 3)) >> 1);
    const float* src = w + (size_t)f * Dn * k;
    int n = Dn * k;
    float mx = 0.f;
    for (int e = tid; e < n; e += 256) {
      float v = src[e];
      sf[e] = v;
      mx = fmaxf(mx, fabsf(v));
    }
    #pragma unroll
    for (int off = 32; off; off >>= 1) mx = fmaxf(mx, __shfl_xor(mx, off));
    if (lane == 0) smax[wv] = mx;
    __syncthreads();
    float M = fmaxf(fmaxf(smax[0], smax[1]), fmaxf(smax[2], smax[3]));
    M = fmaxf(M, 1e-30f);
    if (tid == 0) fscale[br * 256 + f] = M / 127.f;
    float qs = 127.f / M;
    for (int j = 0; j < k; ++j) {
      signed char* dst = wq + (size_t)(mBase + j * 256 + f) * Dn;
      for (int d4 = tid * 4; d4 < Dn; d4 += 1024) {
        char4 o = { q8(sf[(d4 + 0) * k + j], qs), q8(sf[(d4 + 1) * k + j], qs),
                    q8(sf[(d4 + 2) * k + j], qs), q8(sf[(d4 + 3) * k + j], qs) };
        *(char4*)(dst + d4) = o;
      }
    }
  }
}

// ---------------------------------------------------------------------------
// 1.5) fill: 64 blocks; prefix + per-batch rowmap slice + feats zeroing.
// ---------------------------------------------------------------------------
__global__ __launch_bounds__(256) void fill_kernel(
    const int* __restrict__ Lbuf, int* __restrict__ plan,
    int* __restrict__ rowmap, int* __restrict__ feats) {
  __shared__ int sOff[65];
  __shared__ int sL[64];
  int tid = threadIdx.x;
  int b = blockIdx.x;
  {
    int4 z = {0, 0, 0, 0};
    *(int4*)(feats + b * 1024 + tid * 4) = z;   // 256 thr x 4 = 1024 ints
  }
  if (tid < 64) {
    int L = Lbuf[tid];
    int SL = (L + 15) & ~15;
    int pre = SL;
    #pragma unroll
    for (int off = 1; off < 64; off <<= 1) {
      int y = __shfl_up(pre, off);
      if (tid >= off) pre += y;
    }
    sOff[tid] = pre - SL;           // exclusive prefix
    sL[tid] = L;
    if (tid == 63) sOff[64] = pre;
  }
  __syncthreads();
  int off = sOff[b], L = sL[b];
  int SL = (L + 15) & ~15;
  int enc = (b << 20) | (L << 10);
  for (int t = tid; t < SL; t += 256) rowmap[off + t] = enc | t;
  if (b == 0) {
    int M = sOff[64];
    if (tid == 0) plan[0] = (M + 255) >> 8;
    for (int p = M + tid; p < M + 264; p += 256)
      rowmap[p] = 512;              // sentinel: b=0, L=0, t=512
  }
}

// ---------------------------------------------------------------------------
// 3) packed-M conv-GEMM, int8 16x16x64, 8 waves of 64t x 64f.
//    B NEVER touches LDS: per d0, each wave batch-loads ALL kk taps' B
//    fragments global(L2)->reg (compiler inserts exact counted vmcnt per
//    tap). A in LDS (dbuf, global_load_lds); ONE __syncthreads per d0 whose
//    implicit vmcnt(0) is exactly the A-landing requirement (B already
//    consumed). Barrier-free taps software-pipeline: MFMA hides A-ds_read
//    and residual L2 latency.
// ---------------------------------------------------------------------------
template<int KK>
static __device__ __forceinline__ void computeD0(
    int d0, const char* sA, const char* const (&gB)[4],
    int wr, int lrow, int lg, iv4 (&acc)[4][4]) {
  int doff = d0 * 64;
  iv4 Bv[5][4];
  #pragma unroll
  for (int j = 0; j < KK; ++j)
    #pragma unroll
    for (int n = 0; n < 4; ++n)
      Bv[j][n] = *(const iv4*)(gB[n] + j * JSTRIDE + doff);
  const char* curA = sA + (d0 & 1) * ABUF;
  #pragma unroll
  for (int j = 0; j < KK; ++j) {
    iv4 Af[4];
    #pragma unroll
    for (int m = 0; m < 4; ++m) {
      int row = wr * 64 + m * 16 + lrow + j;        // +j = the conv shift
      Af[m] = *(const iv4*)(curA + row * 64 + ((lg ^ ((row >> 1) & 3)) << 4));
    }
    __builtin_amdgcn_s_setprio(1);
    #pragma unroll
    for (int n = 0; n < 4; ++n)
      #pragma unroll
      for (int m = 0; m < 4; ++m)
        acc[m][n] = __builtin_amdgcn_mfma_i32_16x16x64_i8(Af[m], Bv[j][n], acc[m][n], 0, 0, 0);
    __builtin_amdgcn_s_setprio(0);
  }
}

static __device__ __forceinline__ void issueA(
    int d0i, char* sA, const char* const (&gA)[2], const char* gAt,
    int lane, int wvoff) {
  int aoff = (d0i + 1) * 64;
  char* nA = sA + ((d0i + 1) & 1) * ABUF;
  gload16(gA[0] + aoff, nA + wvoff);
  gload16(gA[1] + aoff, nA + 8192 + wvoff);
  if (lane < 16) gload16(gAt + aoff, nA + 16384);   // rows 256..259 (waves dup)
}

template<int KK>
static __device__ __forceinline__ void conv_loop(
    char* sA, const char* const (&gA)[2], const char* gAt,
    const char* const (&gB)[4],
    int lane, int wr, int lrow, int lg, int wvoff, iv4 (&acc)[4][4]) {
  // prologue: stage A(0); barrier drains it
  gload16(gA[0], sA + wvoff);
  gload16(gA[1], sA + 8192 + wvoff);
  if (lane < 16) gload16(gAt, sA + 16384);
  __syncthreads();
  for (int d0 = 0; d0 < 11; ++d0) {
    issueA(d0, sA, gA, gAt, lane, wvoff);           // A(d0+1) -> alt buf
    computeD0<KK>(d0, sA, gB, wr, lrow, lg, acc);
    __syncthreads();                // implicit vmcnt(0): A(d0+1) landed
  }
  computeD0<KK>(11, sA, gB, wr, lrow, lg, acc);
}

__global__ __launch_bounds__(512) void conv_kernel(
    const signed char* __restrict__ hcq, const signed char* __restrict__ wq,
    const float* __restrict__ b2, const float* __restrict__ b3,
    const float* __restrict__ b4, const float* __restrict__ b5,
    const float* __restrict__ fscale,
    const int* __restrict__ plan, const int* __restrict__ rowmap,
    int* __restrict__ feats) {
  __shared__ char smem[2 * ABUF];   // 33,280 B (A dbuf only)
  char* sA = smem;
  int idx = blockIdx.x;
  // XCD-aware decode: tile ≡ xcd (mod 8) so all 8 subs of a tile share an XCD
  int xcd = idx & 7, s2 = idx >> 3;
  int sub = s2 & 7, tile = xcd + ((s2 >> 3) << 3);
  if (tile >= plan[0]) return;
  int br = 3 - (sub >> 1), ff = sub & 1, kk = br + 2;
  int mBase = 256 * ((br * (br + 3)) >> 1) + ff * 128;
  const float* bias = (br == 0) ? b2 : (br == 1) ? b3 : (br == 2) ? b4 : b5;
  int tid = threadIdx.x, lane = tid & 63, wv = tid >> 6;
  int wr = wv >> 1, wc = wv & 1;     // wave tile: 64t x 64f
  int lrow = lane & 15, lg = lane >> 4;
  int wvoff = wv * 1024;
  int P0 = tile << 8;                // 256 rows per tile

  // per-lane pre-swizzled global sources for A (d0-invariant)
  const char* gA[2];
  #pragma unroll
  for (int p = 0; p < 2; ++p) {
    int c = p * 512 + tid;
    int row = c >> 2, sgp = c & 3;
    int rm = rowmap[P0 + row];
    int bb_ = rm >> 20, t = rm & 1023;
    int seg = sgp ^ ((row >> 1) & 3);
    gA[p] = (const char*)(hcq + ((size_t)(bb_ * SPn + t)) * Dn + seg * 16);
  }
  const char* gAt;
  {
    int l = lane & 15;               // rows 256..259 (lanes<16, all waves dup)
    int row = 256 + (l >> 2), sgp = l & 3;
    int rm = rowmap[P0 + row];
    int bb_ = rm >> 20, t = rm & 1023;
    int seg = sgp ^ ((row >> 1) & 3);
    gAt = (const char*)(hcq + ((size_t)(bb_ * SPn + t)) * Dn + seg * 16);
  }
  // per-lane B sources: direct global->reg, no swizzle. Wave reads a
  // 16-row x 64B tile per fragment (16 x 64B L2 segments).
  const char* gB[4];
  #pragma unroll
  for (int n = 0; n < 4; ++n)
    gB[n] = (const char*)(wq + (size_t)(mBase + wc * 64 + n * 16 + lrow) * Dn + lg * 16);

  iv4 acc[4][4];
  #pragma unroll
  for (int m = 0; m < 4; ++m)
    #pragma unroll
    for (int n = 0; n < 4; ++n) acc[m][n] = (iv4)0;

  switch (br) {
    case 3: conv_loop<5>(sA, gA, gAt, gB, lane, wr, lrow, lg, wvoff, acc); break;
    case 2: conv_loop<4>(sA, gA, gAt, gB, lane, wr, lrow, lg, wvoff, acc); break;
    case 1: conv_loop<3>(sA, gA, gAt, gB, lane, wr, lrow, lg, wvoff, acc); break;
    default: conv_loop<2>(sA, gA, gAt, gB, lane, wr, lrow, lg, wvoff, acc); break;
  }

  // epilogue: dequant (s_a * s_f) + bias + mask + relu + pool + atomic
  int rmv[4];
  #pragma unroll
  for (int m = 0; m < 4; ++m) rmv[m] = rowmap[P0 + wr * 64 + m * 16];
  #pragma unroll
  for (int n = 0; n < 4; ++n) {
    int fg = ff * 128 + wc * 64 + n * 16 + lrow;
    float bv = bias[fg];
    float sfc = fscale[br * 256 + fg] * SAQ;
    #pragma unroll
    for (int m = 0; m < 4; ++m) {
      int bb_ = rmv[m] >> 20;
      int Lb = (rmv[m] >> 10) & 1023;
      int t0 = (rmv[m] & 1023) + lg * 4;
      int vlim = Lb - kk + 1;
      float pmax = 0.f;
      #pragma unroll
      for (int i = 0; i < 4; ++i) {
        float v = (float)acc[m][n][i] * sfc + bv;
        pmax = fmaxf(pmax, (t0 + i < vlim) ? fmaxf(v, 0.f) : 0.f);
      }
      pmax = fmaxf(pmax, __shfl_xor(pmax, 16));
      pmax = fmaxf(pmax, __shfl_xor(pmax, 32));
      if (lane < 16 && pmax > 0.f)
        atomicMax(feats + bb_ * 1024 + br * 256 + fg, __float_as_int(pmax));
    }
  }
}

// ---------------------------------------------------------------------------
// 4) FC + sigmoid
// ---------------------------------------------------------------------------
__global__ __launch_bounds__(64) void fc_kernel(
    const int* __restrict__ feats, const float* __restrict__ fcw,
    const float* __restrict__ fcb, float* __restrict__ out) {
  int b = blockIdx.x, lane = threadIdx.x;
  float acc = 0.f;
  for (int i = lane; i < 1024; i += 64)
    acc += __int_as_float(feats[b * 1024 + i]) * fcw[i];
  #pragma unroll
  for (int off = 32; off; off >>= 1) acc += __shfl_xor(acc, off);
  if (lane == 0) out[b] = 1.f / (1.f + expf(-(acc + fcb[0])));
}

extern "C" void kernel_launch(void* const* d_in, const int* in_sizes, int n_in,
                              void* d_out, int out_size, void* d_ws, size_t ws_size,
                              hipStream_t stream) {
  const int*   x   = (const int*)d_in[0];
  const float* h   = (const float*)d_in[1];
  const float* w2  = (const float*)d_in[2];
  const float* b2  = (const float*)d_in[3];
  const float* w3  = (const float*)d_in[4];
  const float* b3  = (const float*)d_in[5];
  const float* w4  = (const float*)d_in[6];
  const float* b4  = (const float*)d_in[7];
  const float* w5  = (const float*)d_in[8];
  const float* b5  = (const float*)d_in[9];
  const float* fcw = (const float*)d_in[10];
  const float* fcb = (const float*)d_in[11];
  float* out = (float*)d_out;
  char* ws = (char*)d_ws;
  signed char* hcq = (signed char*)ws;                    // 64*520*768   = 25,559,040
  signed char* wq  = (signed char*)(ws + 25559040);       // 3584*768     =  2,752,512
  float* fscale = (float*)(ws + 28311552);                // 1024*4
  int* feats  = (int*)(ws + 28315648);                    // 64*1024*4    =    262,144
  int* Lbuf   = (int*)(ws + 28577792);                    // 64*4
  int* plan   = (int*)(ws + 28578048);                    // 4 ints
  int* rowmap = (int*)(ws + 28578064);                    // (32768+264)*4

  stage_kernel<<<1536, 256, 0, stream>>>(x, h, w2, w3, w4, w5, hcq, wq, fscale, Lbuf);
  fill_kernel<<<64, 256, 0, stream>>>(Lbuf, plan, rowmap, feats);
  conv_kernel<<<1024, 512, 0, stream>>>(hcq, wq, b2, b3, b4, b5, fscale, plan, rowmap, feats);
  fc_kernel<<<64, 64, 0, stream>>>(feats, fcw, fcb, out);
}

// Round 20
// 94.269 us; speedup vs baseline: 1.9834x; 1.9834x over previous
//
#include <hip/hip_runtime.h>
#include <stdint.h>

#define Bn 64
#define Sn 512
#define SPn 520
#define Dn 768
#define JSTRIDE 196608   // 256 rows * 768 B : tap stride within wq
#define ABUF 16640       // 260 rows * 64 B
#define BSLOT 8192       // 128 rows * 64 B
#define QS_A 28.222222f  // 127/4.5
#define SAQ 0.035433072f // 4.5/127

typedef int iv4 __attribute__((ext_vector_type(4)));

static __device__ __forceinline__ signed char q8(float f, float s) {
  float t = __builtin_rintf(f * s);
  t = fmaxf(-127.f, fminf(127.f, t));
  return (signed char)(int)t;
}

// async global->LDS, 16B/lane; LDS dest = wave-uniform base + lane*16
static __device__ __forceinline__ void gload16(const void* g, void* l) {
  __builtin_amdgcn_global_load_lds(
      (const __attribute__((address_space(1))) unsigned int*)g,
      (__attribute__((address_space(3))) unsigned int*)l, 16, 0, 0);
}

template<int N> __device__ __forceinline__ void waitv() {
  static_assert(N == 0 || N == 1 || N == 4, "");
  if constexpr (N == 0) asm volatile("s_waitcnt vmcnt(0)" ::: "memory");
  else if constexpr (N == 1) asm volatile("s_waitcnt vmcnt(1)" ::: "memory");
  else asm volatile("s_waitcnt vmcnt(4)" ::: "memory");
}

// ---------------------------------------------------------------------------
// 1) fused stage: blocks [0,512) compact+quant h -> hcq (rblk 0 writes L);
//    [512,1536) wpack
// ---------------------------------------------------------------------------
__global__ __launch_bounds__(256) void stage_kernel(
    const int* __restrict__ x, const float* __restrict__ h,
    const float* __restrict__ w2, const float* __restrict__ w3,
    const float* __restrict__ w4, const float* __restrict__ w5,
    signed char* __restrict__ hcq, signed char* __restrict__ wq,
    float* __restrict__ fscale, int* __restrict__ Lout) {
  int tid = threadIdx.x, lane = tid & 63, wv = tid >> 6;
  if (blockIdx.x < 512) {
    int cidx = blockIdx.x;
    int b = cidx >> 3, rblk = cidx & 7;
    __shared__ unsigned long long masks[8];
    __shared__ short sidx[Sn];
    for (int c = wv; c < 8; c += 4) {
      unsigned long long m = __ballot(x[b * Sn + c * 64 + lane] != 0);
      if (lane == 0) masks[c] = m;
    }
    __syncthreads();
    int pref[9]; pref[0] = 0;
    #pragma unroll
    for (int c = 0; c < 8; ++c) pref[c + 1] = pref[c] + __popcll(masks[c]);
    int L = pref[8];
    if (rblk == 0 && tid == 0) Lout[b] = L;
    for (int p = tid; p < Sn; p += 256) {
      int c = p >> 6, l = p & 63;
      unsigned long long m = masks[c];
      if ((m >> l) & 1ull)
        sidx[pref[c] + __popcll(m & ((1ull << l) - 1ull))] = (short)p;
    }
    __syncthreads();
    int r0 = rblk * 65;  // 8 * 65 = 520 rows
    for (int r = r0 + wv; r < r0 + 65; r += 4) {
      if (r < L) {
        signed char* dst = hcq + ((size_t)b * SPn + r) * Dn;
        const float* src = h + ((size_t)b * Sn + sidx[r]) * Dn;
        #pragma unroll
        for (int c = 0; c < 3; ++c) {
          int d = c * 256 + lane * 4;
          float4 v = *(const float4*)(src + d);
          char4 o = { q8(v.x, QS_A), q8(v.y, QS_A), q8(v.z, QS_A), q8(v.w, QS_A) };
          *(char4*)(dst + d) = o;
        }
      }
    }
  } else {
    __shared__ float sf[3840];
    __shared__ float smax[4];
    int bb = blockIdx.x - 512;
    int br = bb >> 8, f = bb & 255, k = br + 2;
    const float* w = (br == 0) ? w2 : (br == 1) ? w3 : (br == 2) ? w4 : w5;
    int mBase = 256 * ((br * (br + 3)) >> 1);
    const float* src = w + (size_t)f * Dn * k;
    int n = Dn * k;
    float mx = 0.f;
    for (int e = tid; e < n; e += 256) {
      float v = src[e];
      sf[e] = v;
      mx = fmaxf(mx, fabsf(v));
    }
    #pragma unroll
    for (int off = 32; off; off >>= 1) mx = fmaxf(mx, __shfl_xor(mx, off));
    if (lane == 0) smax[wv] = mx;
    __syncthreads();
    float M = fmaxf(fmaxf(smax[0], smax[1]), fmaxf(smax[2], smax[3]));
    M = fmaxf(M, 1e-30f);
    if (tid == 0) fscale[br * 256 + f] = M / 127.f;
    float qs = 127.f / M;
    for (int j = 0; j < k; ++j) {
      signed char* dst = wq + (size_t)(mBase + j * 256 + f) * Dn;
      for (int d4 = tid * 4; d4 < Dn; d4 += 1024) {
        char4 o = { q8(sf[(d4 + 0) * k + j], qs), q8(sf[(d4 + 1) * k + j], qs),
                    q8(sf[(d4 + 2) * k + j], qs), q8(sf[(d4 + 3) * k + j], qs) };
        *(char4*)(dst + d4) = o;
      }
    }
  }
}

// ---------------------------------------------------------------------------
// 1.5) fill: 64 blocks; prefix + per-batch rowmap slice + feats zeroing.
//      Block 0 writes plan (#256-row tiles) + sentinels.
// ---------------------------------------------------------------------------
__global__ __launch_bounds__(256) void fill_kernel(
    const int* __restrict__ Lbuf, int* __restrict__ plan,
    int* __restrict__ rowmap, int* __restrict__ feats) {
  __shared__ int sOff[65];
  __shared__ int sL[64];
  int tid = threadIdx.x;
  int b = blockIdx.x;
  {
    int4 z = {0, 0, 0, 0};
    *(int4*)(feats + b * 1024 + tid * 4) = z;   // 256 thr x 4 = 1024 ints
  }
  if (tid < 64) {
    int L = Lbuf[tid];
    int SL = (L + 15) & ~15;
    int pre = SL;
    #pragma unroll
    for (int off = 1; off < 64; off <<= 1) {
      int y = __shfl_up(pre, off);
      if (tid >= off) pre += y;
    }
    sOff[tid] = pre - SL;           // exclusive prefix
    sL[tid] = L;
    if (tid == 63) sOff[64] = pre;
  }
  __syncthreads();
  int off = sOff[b], L = sL[b];
  int SL = (L + 15) & ~15;
  int enc = (b << 20) | (L << 10);
  for (int t = tid; t < SL; t += 256) rowmap[off + t] = enc | t;
  if (b == 0) {
    int M = sOff[64];
    if (tid == 0) plan[0] = (M + 255) >> 8;
    for (int p = M + tid; p < M + 264; p += 256)
      rowmap[p] = 512;              // sentinel: b=0, L=0, t=512
  }
}

// ---------------------------------------------------------------------------
// 3) packed-M conv-GEMM, int8 16x16x64, 8 waves (wave tile 64t x 64f),
//    counted-vmcnt ring-3 pipeline (round-9/18 best: 67 us). Per wave per
//    step: 1 B gload (+3 A at j0), 8 ds_read_b128, 16 MFMA. W gates per d0:
//    {4,4,1,...}, tail all 1.
// ---------------------------------------------------------------------------
static __device__ __forceinline__ void issueA(
    int d0i, char* sA, const char* const (&gA)[2], const char* gAt,
    int lane, int wvoff) {
  int aoff = (d0i + 1) * 64;
  char* nA = sA + ((d0i + 1) & 1) * ABUF;
  #pragma unroll
  for (int p = 0; p < 2; ++p) gload16(gA[p] + aoff, nA + p * 8192 + wvoff);
  if (lane < 16) gload16(gAt + aoff, nA + 16384);   // rows 256..259 (waves dup)
}

template<int J, int W, int J2, int DADD, int DOA>
static __device__ __forceinline__ void conv_step(
    int d0i, int bsl0, char* sA, char* sB,
    const char* const (&gA)[2], const char* gAt, const char* gB0,
    int lane, int wr, int wc, int lrow, int lg, int wvoff, iv4 (&acc)[4][4]) {
  int sl = bsl0 + J;      sl  -= (sl  >= 3) ? 3 : 0; sl  -= (sl  >= 3) ? 3 : 0;
  int dsl = bsl0 + J + 2; dsl -= (dsl >= 3) ? 3 : 0; dsl -= (dsl >= 3) ? 3 : 0;
  // stage issues (early): B(s+2), then A(d0i+1) at j==0
  {
    int boff = J2 * JSTRIDE + (d0i + DADD) * 64;
    gload16(gB0 + boff, sB + dsl * BSLOT + wvoff);
  }
  if constexpr (DOA) issueA(d0i, sA, gA, gAt, lane, wvoff);
  // ds_read fragments for this step
  const char* curA = sA + (d0i & 1) * ABUF;
  const char* curB = sB + sl * BSLOT;
  iv4 Af[4], Bf[4];
  #pragma unroll
  for (int m = 0; m < 4; ++m) {
    int row = wr * 64 + m * 16 + lrow + J;            // +J = the conv shift
    Af[m] = *(const iv4*)(curA + row * 64 + ((lg ^ ((row >> 1) & 3)) << 4));
  }
  #pragma unroll
  for (int n = 0; n < 4; ++n) {
    int row = wc * 64 + n * 16 + lrow;
    Bf[n] = *(const iv4*)(curB + row * 64 + ((lg ^ ((row >> 1) & 3)) << 4));
  }
  __builtin_amdgcn_s_setprio(1);
  #pragma unroll
  for (int n = 0; n < 4; ++n)
    #pragma unroll
    for (int m = 0; m < 4; ++m)
      acc[m][n] = __builtin_amdgcn_mfma_i32_16x16x64_i8(Af[m], Bf[n], acc[m][n], 0, 0, 0);
  __builtin_amdgcn_s_setprio(0);
  __builtin_amdgcn_sched_barrier(0);
  waitv<W>();                       // counted: own loads for next step landed
  __builtin_amdgcn_sched_barrier(0);
  __builtin_amdgcn_s_barrier();     // whole next slot now valid for all waves
  __builtin_amdgcn_sched_barrier(0);
}

#define SA bsl0, sA, sB, gA, gAt, gB0, lane, wr, wc, lrow, lg, wvoff, acc

template<int KK>
static __device__ __forceinline__ void conv_loop(
    char* sA, char* sB, const char* const (&gA)[2], const char* gAt,
    const char* gB0,
    int lane, int wr, int wc, int lrow, int lg, int wvoff, iv4 (&acc)[4][4]) {
  // prologue: A(0) first, then B slot0 (tap0), slot1 (tap1). FIFO: [A,A,At,B0,B1]
  #pragma unroll
  for (int p = 0; p < 2; ++p) gload16(gA[p], sA + p * 8192 + wvoff);
  if (lane < 16) gload16(gAt, sA + 16384);
  gload16(gB0, sB + wvoff);
  gload16(gB0 + JSTRIDE, sB + BSLOT + wvoff);
  __builtin_amdgcn_sched_barrier(0);
  waitv<1>();                       // A(0)+B(0) landed; B(1) may fly
  __builtin_amdgcn_sched_barrier(0);
  __builtin_amdgcn_s_barrier();
  __builtin_amdgcn_sched_barrier(0);
  int bsl0 = 0;
  for (int d0i = 0; d0i < 11; ++d0i) {
    if constexpr (KK == 5) {
      conv_step<0,4,2,0,1>(d0i, SA);
      conv_step<1,4,3,0,0>(d0i, SA);
      conv_step<2,1,4,0,0>(d0i, SA);
      conv_step<3,1,0,1,0>(d0i, SA);
      conv_step<4,1,1,1,0>(d0i, SA);
    } else if constexpr (KK == 4) {
      conv_step<0,4,2,0,1>(d0i, SA);
      conv_step<1,4,3,0,0>(d0i, SA);
      conv_step<2,1,0,1,0>(d0i, SA);
      conv_step<3,1,1,1,0>(d0i, SA);
    } else if constexpr (KK == 3) {
      conv_step<0,4,2,0,1>(d0i, SA);
      conv_step<1,4,0,1,0>(d0i, SA);
      conv_step<2,1,1,1,0>(d0i, SA);
    } else {
      conv_step<0,4,0,1,1>(d0i, SA);
      conv_step<1,1,1,1,0>(d0i, SA);
    }
    bsl0 += KK; bsl0 -= (bsl0 >= 3) ? 3 : 0; bsl0 -= (bsl0 >= 3) ? 3 : 0;
  }
  // tail d0 = 11: no A issue; all gates W=1 (only B pairs in FIFO)
  if constexpr (KK == 5) {
    conv_step<0,1,2,0,0>(11, SA);
    conv_step<1,1,3,0,0>(11, SA);
    conv_step<2,1,4,0,0>(11, SA);
    conv_step<3,1,0,1,0>(11, SA);
    conv_step<4,1,1,1,0>(11, SA);
  } else if constexpr (KK == 4) {
    conv_step<0,1,2,0,0>(11, SA);
    conv_step<1,1,3,0,0>(11, SA);
    conv_step<2,1,0,1,0>(11, SA);
    conv_step<3,1,1,1,0>(11, SA);
  } else if constexpr (KK == 3) {
    conv_step<0,1,2,0,0>(11, SA);
    conv_step<1,1,0,1,0>(11, SA);
    conv_step<2,1,1,1,0>(11, SA);
  } else {
    conv_step<0,1,0,1,0>(11, SA);
    conv_step<1,1,1,1,0>(11, SA);
  }
  waitv<0>();                       // no DMA may outlive this block's LDS
}

__global__ __launch_bounds__(512, 4) void conv_kernel(
    const signed char* __restrict__ hcq, const signed char* __restrict__ wq,
    const float* __restrict__ b2, const float* __restrict__ b3,
    const float* __restrict__ b4, const float* __restrict__ b5,
    const float* __restrict__ fscale,
    const int* __restrict__ plan, const int* __restrict__ rowmap,
    int* __restrict__ feats) {
  __shared__ char smem[2 * ABUF + 3 * BSLOT];   // 57856 B
  char* sA = smem;
  char* sB = smem + 2 * ABUF;
  int idx = blockIdx.x;
  // XCD-aware decode: tile ≡ xcd (mod 8) so all 8 subs of a tile share an XCD
  int xcd = idx & 7, s2 = idx >> 3;
  int sub = s2 & 7, tile = xcd + ((s2 >> 3) << 3);
  if (tile >= plan[0]) return;
  int br = 3 - (sub >> 1), ff = sub & 1, kk = br + 2;
  int mBase = 256 * ((br * (br + 3)) >> 1) + ff * 128;
  const float* bias = (br == 0) ? b2 : (br == 1) ? b3 : (br == 2) ? b4 : b5;
  int tid = threadIdx.x, lane = tid & 63, wv = tid >> 6;
  int wr = wv >> 1, wc = wv & 1;     // wave tile: 64t x 64f
  int lrow = lane & 15, lg = lane >> 4;
  int wvoff = wv * 1024;
  int P0 = tile << 8;                // 256 rows per tile

  // per-lane pre-swizzled global sources (d0-invariant)
  const char* gA[2];
  #pragma unroll
  for (int p = 0; p < 2; ++p) {
    int c = p * 512 + tid;
    int row = c >> 2, sgp = c & 3;
    int rm = rowmap[P0 + row];
    int bb_ = rm >> 20, t = rm & 1023;
    int seg = sgp ^ ((row >> 1) & 3);
    gA[p] = (const char*)(hcq + ((size_t)(bb_ * SPn + t)) * Dn + seg * 16);
  }
  const char* gAt;
  {
    int l = lane & 15;               // rows 256..259 (lanes<16, all waves dup)
    int row = 256 + (l >> 2), sgp = l & 3;
    int rm = rowmap[P0 + row];
    int bb_ = rm >> 20, t = rm & 1023;
    int seg = sgp ^ ((row >> 1) & 3);
    gAt = (const char*)(hcq + ((size_t)(bb_ * SPn + t)) * Dn + seg * 16);
  }
  const char* gB0;
  {
    int row = tid >> 2, sgp = tid & 3;   // 512 chunks = 128 rows x 4 segs
    int seg = sgp ^ ((row >> 1) & 3);
    gB0 = (const char*)(wq + ((size_t)(mBase + row)) * Dn + seg * 16);
  }

  iv4 acc[4][4];
  #pragma unroll
  for (int m = 0; m < 4; ++m)
    #pragma unroll
    for (int n = 0; n < 4; ++n) acc[m][n] = (iv4)0;

  switch (br) {
    case 3: conv_loop<5>(sA, sB, gA, gAt, gB0, lane, wr, wc, lrow, lg, wvoff, acc); break;
    case 2: conv_loop<4>(sA, sB, gA, gAt, gB0, lane, wr, wc, lrow, lg, wvoff, acc); break;
    case 1: conv_loop<3>(sA, sB, gA, gAt, gB0, lane, wr, wc, lrow, lg, wvoff, acc); break;
    default: conv_loop<2>(sA, sB, gA, gAt, gB0, lane, wr, wc, lrow, lg, wvoff, acc); break;
  }

  // epilogue: dequant (s_a * s_f) + bias + mask + relu + pool + atomic
  int rmv[4];
  #pragma unroll
  for (int m = 0; m < 4; ++m) rmv[m] = rowmap[P0 + wr * 64 + m * 16];
  #pragma unroll
  for (int n = 0; n < 4; ++n) {
    int fg = ff * 128 + wc * 64 + n * 16 + lrow;
    float bv = bias[fg];
    float sfc = fscale[br * 256 + fg] * SAQ;
    #pragma unroll
    for (int m = 0; m < 4; ++m) {
      int bb_ = rmv[m] >> 20;
      int Lb = (rmv[m] >> 10) & 1023;
      int t0 = (rmv[m] & 1023) + lg * 4;
      int vlim = Lb - kk + 1;
      float pmax = 0.f;
      #pragma unroll
      for (int i = 0; i < 4; ++i) {
        float v = (float)acc[m][n][i] * sfc + bv;
        pmax = fmaxf(pmax, (t0 + i < vlim) ? fmaxf(v, 0.f) : 0.f);
      }
      pmax = fmaxf(pmax, __shfl_xor(pmax, 16));
      pmax = fmaxf(pmax, __shfl_xor(pmax, 32));
      if (lane < 16 && pmax > 0.f)
        atomicMax(feats + bb_ * 1024 + br * 256 + fg, __float_as_int(pmax));
    }
  }
}

// ---------------------------------------------------------------------------
// 4) FC + sigmoid
// ---------------------------------------------------------------------------
__global__ __launch_bounds__(64) void fc_kernel(
    const int* __restrict__ feats, const float* __restrict__ fcw,
    const float* __restrict__ fcb, float* __restrict__ out) {
  int b = blockIdx.x, lane = threadIdx.x;
  float acc = 0.f;
  for (int i = lane; i < 1024; i += 64)
    acc += __int_as_float(feats[b * 1024 + i]) * fcw[i];
  #pragma unroll
  for (int off = 32; off; off >>= 1) acc += __shfl_xor(acc, off);
  if (lane == 0) out[b] = 1.f / (1.f + expf(-(acc + fcb[0])));
}

extern "C" void kernel_launch(void* const* d_in, const int* in_sizes, int n_in,
                              void* d_out, int out_size, void* d_ws, size_t ws_size,
                              hipStream_t stream) {
  const int*   x   = (const int*)d_in[0];
  const float* h   = (const float*)d_in[1];
  const float* w2  = (const float*)d_in[2];
  const float* b2  = (const float*)d_in[3];
  const float* w3  = (const float*)d_in[4];
  const float* b3  = (const float*)d_in[5];
  const float* w4  = (const float*)d_in[6];
  const float* b4  = (const float*)d_in[7];
  const float* w5  = (const float*)d_in[8];
  const float* b5  = (const float*)d_in[9];
  const float* fcw = (const float*)d_in[10];
  const float* fcb = (const float*)d_in[11];
  float* out = (float*)d_out;
  char* ws = (char*)d_ws;
  signed char* hcq = (signed char*)ws;                    // 64*520*768   = 25,559,040
  signed char* wq  = (signed char*)(ws + 25559040);       // 3584*768     =  2,752,512
  float* fscale = (float*)(ws + 28311552);                // 1024*4
  int* feats  = (int*)(ws + 28315648);                    // 64*1024*4    =    262,144
  int* Lbuf   = (int*)(ws + 28577792);                    // 64*4
  int* plan   = (int*)(ws + 28578048);                    // 4 ints
  int* rowmap = (int*)(ws + 28578064);                    // (32768+264)*4

  stage_kernel<<<1536, 256, 0, stream>>>(x, h, w2, w3, w4, w5, hcq, wq, fscale, Lbuf);
  fill_kernel<<<64, 256, 0, stream>>>(Lbuf, plan, rowmap, feats);
  conv_kernel<<<1024, 512, 0, stream>>>(hcq, wq, b2, b3, b4, b5, fscale, plan, rowmap, feats);
  fc_kernel<<<64, 64, 0, stream>>>(feats, fcw, fcb, out);
}